// Round 9
// baseline (315.808 us; speedup 1.0000x reference)
//
#include <hip/hip_runtime.h>
#include <math.h>

// ---------------------------------------------------------------------------
// GCN: h1 = relu(Agg(x@W1)+b1); h2 = relu(Agg(h1@W2)+b2); out = sigmoid(h2@Wfc+bfc)
// Agg(xl)[dst] = dinv[dst] * ( sum_{src->dst} xl_s[src] + xl_s[dst] )
//   where xl_s[n] = (x@W)[n] * dinv[n]   (source-side norm folded into GEMM)
// R11-R14: node-per-slot gather aggs + fused gemm2 (215.7us).
// R15-R19: depth/shape/balance/sort/NT all NULL or regress =>
//   agg tput = per-CU inflight cap / avg latency; latency set by L2-miss frac.
// R20/R21: fp8 e4m3 gather tables both layers (12.8->6.4MB each) -> 203.9us,
//   aggs ~41.5->~30 each. absmax 0.0039 (passes).
// R22: CSR build rewritten with direct GLOBAL atomics (L2-side, ~16/addr):
//   zero+deg+part+scan_tot+fix+fill replaces hist+colscan+scan_tot+scatter+
//   bucket. Drops the 6.4MB ebuf intermediate (19MB round-trip) and ~3.2M
//   LDS atomics + two 512-scans of k_bucket. Aggs/gemm unchanged.
// ---------------------------------------------------------------------------

typedef __attribute__((ext_vector_type(8))) short bf16x8;
typedef __attribute__((ext_vector_type(4))) float f32x4;
typedef __attribute__((ext_vector_type(2))) float f32x2;

#define CHUNKS 1024

__device__ __forceinline__ unsigned short f2bf(float f) {
    unsigned u = __float_as_uint(f);
    u += 0x7FFFu + ((u >> 16) & 1u);   // round-to-nearest-even
    return (unsigned short)(u >> 16);
}
__device__ __forceinline__ unsigned packbf(float a, float b) {
    return (unsigned)f2bf(a) | ((unsigned)f2bf(b) << 16);
}
// fp8 e4m3 (OCP on gfx950) encode/decode via HW converts
__device__ __forceinline__ unsigned char f2fp8(float f) {
    return (unsigned char)(__builtin_amdgcn_cvt_pk_fp8_f32(f, f, 0u, false) & 0xFFu);
}
// accumulate 8 fp8 (one uint2) into 4 packed f32x2 accumulators
__device__ __forceinline__ void fp8add(uint2 g, f32x2* a) {
    a[0] += __builtin_amdgcn_cvt_pk_f32_fp8((int)g.x, false);
    a[1] += __builtin_amdgcn_cvt_pk_f32_fp8((int)g.x, true);
    a[2] += __builtin_amdgcn_cvt_pk_f32_fp8((int)g.y, false);
    a[3] += __builtin_amdgcn_cvt_pk_f32_fp8((int)g.y, true);
}

// ---- R22 CSR build: direct global-atomic counting sort --------------------
__global__ __launch_bounds__(256) void k_zero(int* __restrict__ deg, int N) {
    int i = blockIdx.x * 256 + threadIdx.x;
    if (i < N) deg[i] = 0;
}

__global__ __launch_bounds__(256) void k_deg(const int* __restrict__ col, int E, int CH,
                                             int* __restrict__ deg) {
    int base = blockIdx.x * CH, hi = min(base + CH, E);
    for (int e = base + (int)threadIdx.x; e < hi; e += 256)
        atomicAdd(&deg[col[e]], 1);
}

// per-512-node bucket: exclusive scan of deg -> local row_off; dinv; cur=0
__global__ __launch_bounds__(512) void k_part(const int* __restrict__ deg, int N,
                                              int* __restrict__ row_off,
                                              float* __restrict__ dinv,
                                              int* __restrict__ cur,
                                              int* __restrict__ bucketTotal) {
    __shared__ int s[512];
    const int b = blockIdx.x, t = threadIdx.x;
    const int node = b * 512 + t;
    int d = (node < N) ? deg[node] : 0;
    s[t] = d;
    __syncthreads();
    for (int off = 1; off < 512; off <<= 1) {
        int u = (t >= off) ? s[t - off] : 0;
        __syncthreads();
        s[t] += u;
        __syncthreads();
    }
    if (node < N) {
        row_off[node] = s[t] - d;              // local exclusive (fixed later)
        dinv[node] = rsqrtf((float)(d + 1));   // +1 self loop
        cur[node] = 0;
    }
    if (t == 511) bucketTotal[b] = s[t];
}

__global__ __launch_bounds__(256) void k_scan_tot(const int* __restrict__ bucketTotal,
                                                  int NBUK, int E, int N,
                                                  int* __restrict__ bucketBase,
                                                  int* __restrict__ row_off) {
    __shared__ int s[256];
    int t = threadIdx.x;
    int v = (t < NBUK) ? bucketTotal[t] : 0;
    s[t] = v;
    __syncthreads();
    for (int off = 1; off < 256; off <<= 1) {
        int u = (t >= off) ? s[t - off] : 0;
        __syncthreads();
        s[t] += u;
        __syncthreads();
    }
    if (t < NBUK) bucketBase[t] = s[t] - v;
    if (t == 0) row_off[N] = E;
}

__global__ __launch_bounds__(512) void k_fix(int N, const int* __restrict__ bucketBase,
                                             int* __restrict__ row_off) {
    int node = blockIdx.x * 512 + (int)threadIdx.x;
    if (node < N) row_off[node] += bucketBase[blockIdx.x];
}

__global__ __launch_bounds__(256) void k_fill(const int* __restrict__ row,
                                              const int* __restrict__ col, int E, int CH,
                                              const int* __restrict__ row_off,
                                              int* __restrict__ cur,
                                              int* __restrict__ csr_src) {
    int base = blockIdx.x * CH, hi = min(base + CH, E);
    for (int e = base + (int)threadIdx.x; e < hi; e += 256) {
        int d = col[e];
        int pos = atomicAdd(&cur[d], 1);
        csr_src[row_off[d] + pos] = row[e];
    }
}

// ---- MFMA GEMM layer 1: xl = fp8((x@W1)*dinv) -----------------------------
template <int K>
__global__ __launch_bounds__(256) void k_gemm_mfma(const float* __restrict__ xf,
                                                   const float* __restrict__ W,
                                                   const float* __restrict__ dinv,
                                                   unsigned char* __restrict__ out,
                                                   int N) {
    constexpr int KS = K + 8;
    __shared__ short sX[64 * KS];
    __shared__ short sW[64 * KS];
    const int tid = threadIdx.x;
    const int wv = tid >> 6, lane = tid & 63;
    const int q = lane >> 4, m = lane & 15;
    const int nb = blockIdx.x * 64;

    for (int i = tid; i < K * 64; i += 256) {
        int k = i >> 6, c = i & 63;
        sW[c * KS + k] = (short)f2bf(W[i]);
    }
    for (int i = tid; i < 64 * (K / 8); i += 256) {
        int r = i / (K / 8), c8 = (i % (K / 8)) * 8;
        int node = nb + r;
        uint4 v = make_uint4(0u, 0u, 0u, 0u);
        if (node < N) {
            float4 lo = *(const float4*)(xf + (size_t)node * K + c8);
            float4 hi = *(const float4*)(xf + (size_t)node * K + c8 + 4);
            v.x = packbf(lo.x, lo.y);
            v.y = packbf(lo.z, lo.w);
            v.z = packbf(hi.x, hi.y);
            v.w = packbf(hi.z, hi.w);
        }
        *(uint4*)(&sX[r * KS + c8]) = v;
    }
    __syncthreads();

    f32x4 acc[4] = {};
    const short* aRow = &sX[(wv * 16 + m) * KS + q * 8];
#pragma unroll
    for (int k0 = 0; k0 < K; k0 += 32) {
        bf16x8 a = *(const bf16x8*)(aRow + k0);
#pragma unroll
        for (int ft = 0; ft < 4; ++ft) {
            bf16x8 b = *(const bf16x8*)(&sW[(ft * 16 + m) * KS + k0 + q * 8]);
            acc[ft] = __builtin_amdgcn_mfma_f32_16x16x32_bf16(a, b, acc[ft], 0, 0, 0);
        }
    }
#pragma unroll
    for (int r = 0; r < 4; ++r) {
        int node = nb + wv * 16 + q * 4 + r;
        if (node < N) {
            float di = dinv[node];
#pragma unroll
            for (int ft = 0; ft < 4; ++ft)
                out[(size_t)node * 64 + ft * 16 + m] = f2fp8(acc[ft][r] * di);
        }
    }
}

// ---- fused layer-1 agg + gemm2 (fp8 gather table, fp8 xl2 output) ---------
__global__ __launch_bounds__(256) void k_agg_g2(const unsigned char* __restrict__ xl,
                                                const int* __restrict__ row_off,
                                                const int* __restrict__ csr_src,
                                                const float* __restrict__ dinv,
                                                const float* __restrict__ bias,
                                                const float* __restrict__ W2,
                                                unsigned char* __restrict__ out, int N) {
    constexpr int KS = 72;               // 64 + 8 pad (bf16 elems)
    __shared__ short sH[4 * 16 * KS];    // per-wave 16x64 A-tiles (9KB)
    __shared__ short sW2[64 * KS];       // W2^T bf16 (9KB)
    const int tid = threadIdx.x;
    const int wv = tid >> 6, lane = tid & 63;
    const int s = lane >> 3, o = lane & 7;
    const int q = lane >> 4, m = lane & 15;

    // stage W2 transposed bf16: sW2[n*KS+k] = bf16(W2[k*64+n])
    for (int i = tid; i < 64 * 64; i += 256) {
        int k = i >> 6, n = i & 63;
        sW2[n * KS + k] = (short)f2bf(W2[i]);
    }
    // zero this wave's A-tile rows 8-15 (never written by gather phase)
    short* myH = &sH[wv * 16 * KS];
    for (int i = lane; i < 8 * KS / 4; i += 64)
        ((unsigned long long*)(myH + 8 * KS))[i] = 0ull;
    __syncthreads();                     // sW2 visible to all waves

    const int base8 = (blockIdx.x * 4 + wv) * 8;
    int node = base8 + s;
    const bool active = node < N;
    node = min(node, N - 1);
    const int beg = row_off[node];
    const int deg = row_off[node + 1] - beg;
    const int cnt = active ? deg + 1 : 0;
    int mx = cnt;
    mx = max(mx, __shfl_xor(mx, 8, 64));
    mx = max(mx, __shfl_xor(mx, 16, 64));
    mx = max(mx, __shfl_xor(mx, 32, 64));
    const char* xlb = (const char*)xl;
    const unsigned loff = (unsigned)(o << 3);          // 8B per octet
    f32x2 acc0[4] = {}, acc1[4] = {};
    int idx[4];
#pragma unroll
    for (int j = 0; j < 4; ++j) idx[j] = (j < deg) ? csr_src[beg + j] : node;
    for (int it = 0; it < mx; it += 4) {
        int c[4];
        bool v[4];
#pragma unroll
        for (int j = 0; j < 4; ++j) {
            c[j] = idx[j];
            v[j] = (it + j) < cnt;
            idx[j] = (it + 4 + j < deg) ? csr_src[beg + it + 4 + j] : node;
        }
        uint2 g0 = *(const uint2*)(xlb + (((unsigned)c[0] << 6) | loff));
        uint2 g1 = *(const uint2*)(xlb + (((unsigned)c[1] << 6) | loff));
        uint2 g2 = *(const uint2*)(xlb + (((unsigned)c[2] << 6) | loff));
        uint2 g3 = *(const uint2*)(xlb + (((unsigned)c[3] << 6) | loff));
        if (!v[0]) g0 = make_uint2(0u, 0u);
        if (!v[1]) g1 = make_uint2(0u, 0u);
        if (!v[2]) g2 = make_uint2(0u, 0u);
        if (!v[3]) g3 = make_uint2(0u, 0u);
        fp8add(g0, acc0);
        fp8add(g1, acc1);
        fp8add(g2, acc0);
        fp8add(g3, acc1);
    }
#pragma unroll
    for (int j = 0; j < 4; ++j) acc0[j] += acc1[j];
    // h1 row -> LDS A-tile (bf16), row = slot s
    {
        float di = dinv[node];
        float4 blo = *(const float4*)(bias + o * 8);
        float4 bhi = *(const float4*)(bias + o * 8 + 4);
        uint4 h;
        h.x = packbf(fmaxf(acc0[0].x * di + blo.x, 0.f), fmaxf(acc0[0].y * di + blo.y, 0.f));
        h.y = packbf(fmaxf(acc0[1].x * di + blo.z, 0.f), fmaxf(acc0[1].y * di + blo.w, 0.f));
        h.z = packbf(fmaxf(acc0[2].x * di + bhi.x, 0.f), fmaxf(acc0[2].y * di + bhi.y, 0.f));
        h.w = packbf(fmaxf(acc0[3].x * di + bhi.z, 0.f), fmaxf(acc0[3].y * di + bhi.w, 0.f));
        *(uint4*)(myH + s * KS + o * 8) = h;     // same-wave LDS, no barrier
    }
    // gemm2: 8 MFMA (4 feat-tiles x K=64)
    f32x4 accm[4] = {};
#pragma unroll
    for (int k0 = 0; k0 < 64; k0 += 32) {
        bf16x8 a = *(const bf16x8*)(myH + m * KS + q * 8 + k0);
#pragma unroll
        for (int ft = 0; ft < 4; ++ft) {
            bf16x8 b = *(const bf16x8*)(&sW2[(ft * 16 + m) * KS + k0 + q * 8]);
            accm[ft] = __builtin_amdgcn_mfma_f32_16x16x32_bf16(a, b, accm[ft], 0, 0, 0);
        }
    }
    if (q < 2) {                          // valid rows 0..7
#pragma unroll
        for (int r = 0; r < 4; ++r) {
            int node2 = base8 + q * 4 + r;
            if (node2 < N) {
                float di2 = dinv[node2];
#pragma unroll
                for (int ft = 0; ft < 4; ++ft)
                    out[(size_t)node2 * 64 + ft * 16 + m] = f2fp8(accm[ft][r] * di2);
            }
        }
    }
}

// Layer-2 agg + final FC + sigmoid (fp8 table, 4-way chains).
__global__ __launch_bounds__(256) void k_agg_fc(const unsigned char* __restrict__ xl,
                                                const int* __restrict__ row_off,
                                                const int* __restrict__ csr_src,
                                                const float* __restrict__ dinv,
                                                const float* __restrict__ bias,
                                                const float* __restrict__ Wfc,
                                                const float* __restrict__ bfc,
                                                float* __restrict__ out, int N) {
    const int wave = threadIdx.x >> 6, lane = threadIdx.x & 63;
    const int s = lane >> 3, o = lane & 7;
    int node = (blockIdx.x * 4 + wave) * 8 + s;
    const bool active = node < N;
    node = min(node, N - 1);
    const int beg = row_off[node];
    const int deg = row_off[node + 1] - beg;
    const int cnt = active ? deg + 1 : 0;
    int mx = cnt;
    mx = max(mx, __shfl_xor(mx, 8, 64));
    mx = max(mx, __shfl_xor(mx, 16, 64));
    mx = max(mx, __shfl_xor(mx, 32, 64));
    const char* xlb = (const char*)xl;
    const unsigned loff = (unsigned)(o << 3);          // 8B per octet
    f32x2 acc0[4] = {}, acc1[4] = {};
    int idx[4];
#pragma unroll
    for (int j = 0; j < 4; ++j) idx[j] = (j < deg) ? csr_src[beg + j] : node;
    for (int it = 0; it < mx; it += 4) {
        int c[4];
        bool v[4];
#pragma unroll
        for (int j = 0; j < 4; ++j) {
            c[j] = idx[j];
            v[j] = (it + j) < cnt;
            idx[j] = (it + 4 + j < deg) ? csr_src[beg + it + 4 + j] : node;
        }
        uint2 g0 = *(const uint2*)(xlb + (((unsigned)c[0] << 6) | loff));
        uint2 g1 = *(const uint2*)(xlb + (((unsigned)c[1] << 6) | loff));
        uint2 g2 = *(const uint2*)(xlb + (((unsigned)c[2] << 6) | loff));
        uint2 g3 = *(const uint2*)(xlb + (((unsigned)c[3] << 6) | loff));
        if (!v[0]) g0 = make_uint2(0u, 0u);
        if (!v[1]) g1 = make_uint2(0u, 0u);
        if (!v[2]) g2 = make_uint2(0u, 0u);
        if (!v[3]) g3 = make_uint2(0u, 0u);
        fp8add(g0, acc0);
        fp8add(g1, acc1);
        fp8add(g2, acc0);
        fp8add(g3, acc1);
    }
#pragma unroll
    for (int j = 0; j < 4; ++j) acc0[j] += acc1[j];
    const float di = dinv[node];
    float4 blo = *(const float4*)(bias + o * 8);
    float4 bhi = *(const float4*)(bias + o * 8 + 4);
    float4 wlo = *(const float4*)(Wfc + o * 8);
    float4 whi = *(const float4*)(Wfc + o * 8 + 4);
    float v = 0.f;
    v += fmaxf(acc0[0].x * di + blo.x, 0.f) * wlo.x;
    v += fmaxf(acc0[0].y * di + blo.y, 0.f) * wlo.y;
    v += fmaxf(acc0[1].x * di + blo.z, 0.f) * wlo.z;
    v += fmaxf(acc0[1].y * di + blo.w, 0.f) * wlo.w;
    v += fmaxf(acc0[2].x * di + bhi.x, 0.f) * whi.x;
    v += fmaxf(acc0[2].y * di + bhi.y, 0.f) * whi.y;
    v += fmaxf(acc0[3].x * di + bhi.z, 0.f) * whi.z;
    v += fmaxf(acc0[3].y * di + bhi.w, 0.f) * whi.w;
    v += __shfl_xor(v, 1, 64);
    v += __shfl_xor(v, 2, 64);
    v += __shfl_xor(v, 4, 64);
    if (active && o == 0) out[node] = 1.f / (1.f + expf(-(v + bfc[0])));
}

extern "C" void kernel_launch(void* const* d_in, const int* in_sizes, int n_in,
                              void* d_out, int out_size, void* d_ws, size_t ws_size,
                              hipStream_t stream) {
    const float* x   = (const float*)d_in[0];
    const int*   ei  = (const int*)d_in[1];   // [2, E]: row then col
    const float* W1  = (const float*)d_in[2];
    const float* b1  = (const float*)d_in[3];
    const float* W2  = (const float*)d_in[4];
    const float* b2  = (const float*)d_in[5];
    const float* Wfc = (const float*)d_in[6];
    const float* bfc = (const float*)d_in[7];
    float* out = (float*)d_out;

    const int H = in_sizes[3];          // 64
    const int D = in_sizes[2] / H;      // 128
    const int N = in_sizes[0] / D;      // 100000
    const int E = in_sizes[1] / 2;      // 1600000
    const int* row = ei;
    const int* col = ei + E;
    const int NBUK = (N + 511) >> 9;    // 196 buckets of 512 nodes
    const int CH   = (E + CHUNKS - 1) / CHUNKS;

    // Workspace carve-up (256B aligned slices)
    char* p = (char*)d_ws;
    auto carve = [&](size_t bytes) {
        char* r = p;
        p += (bytes + 255) & ~(size_t)255;
        return (void*)r;
    };
    int*            deg         = (int*)carve((size_t)N * 4);
    int*            cur         = (int*)carve((size_t)N * 4);
    int*            bucketTotal = (int*)carve((size_t)256 * 4);
    int*            bucketBase  = (int*)carve((size_t)256 * 4);
    int*            csr_src     = (int*)carve((size_t)E * 4);
    int*            row_off     = (int*)carve((size_t)(N + 1) * 4);
    float*          dinv        = (float*)carve((size_t)N * 4);
    unsigned char*  bufXL8      = (unsigned char*)carve((size_t)N * 64);
    unsigned char*  bufXL2      = (unsigned char*)carve((size_t)N * 64);
    (void)ws_size;

    const int TB = 256;
    // 1. CSR build (direct global-atomic counting sort)
    k_zero<<<(N + 255) / 256, TB, 0, stream>>>(deg, N);
    k_deg<<<CHUNKS, TB, 0, stream>>>(col, E, CH, deg);
    k_part<<<NBUK, 512, 0, stream>>>(deg, N, row_off, dinv, cur, bucketTotal);
    k_scan_tot<<<1, TB, 0, stream>>>(bucketTotal, NBUK, E, N, bucketBase, row_off);
    k_fix<<<NBUK, 512, 0, stream>>>(N, bucketBase, row_off);
    k_fill<<<CHUNKS, TB, 0, stream>>>(row, col, E, CH, row_off, cur, csr_src);

    int gemmGrid = (N + 63) / 64;       // 1563
    int aggGrid  = (N + 31) / 32;       // 3125 (8 nodes/wave x 4 waves)
    // 2. layer 1 GEMM: xl = fp8((x@W1)*dinv)
    k_gemm_mfma<128><<<gemmGrid, TB, 0, stream>>>(x, W1, dinv, bufXL8, N);
    // 3. fused layer-1 agg + gemm2: xl2 = fp8(dinv*(relu(dinv*Agg(xl)+b1)@W2))
    k_agg_g2<<<aggGrid, TB, 0, stream>>>(bufXL8, row_off, csr_src, dinv, b1, W2, bufXL2, N);
    // 4. layer-2 agg + FC + sigmoid
    k_agg_fc<<<aggGrid, TB, 0, stream>>>(bufXL2, row_off, csr_src, dinv, b2, Wfc, bfc, out, N);
}

// Round 10
// 213.215 us; speedup vs baseline: 1.4812x; 1.4812x over previous
//
#include <hip/hip_runtime.h>
#include <math.h>

// ---------------------------------------------------------------------------
// GCN: h1 = relu(Agg(x@W1)+b1); h2 = relu(Agg(h1@W2)+b2); out = sigmoid(h2@Wfc+bfc)
// Agg(xl)[dst] = dinv[dst] * ( sum_{src->dst} xl_s[src] + xl_s[dst] )
//   where xl_s[n] = (x@W)[n] * dinv[n]   (source-side norm folded into GEMM)
// R11-R14: node-per-slot gather aggs + fused gemm2 (215.7us).
// R15-R19: depth/shape/balance/sort/NT all NULL or regress =>
//   agg tput = per-CU inflight cap / avg latency; latency set by L2-miss frac.
// R20/R21: fp8 e4m3 gather tables both layers -> 203.9us, absmax 0.0039.
// R22: global-atomic CSR (k_fill) -> 115us REGRESSION: atomic-with-return +
//   dependent random store is ~10x the LDS-bucketed two-phase. REVERTED.
// R23: R21 CSR build, but BUCKET SIZE 512 -> 128 nodes: k_bucket goes from
//   196 blocks (<1/CU, serial-time-bound: ~8200 edges + 512-wide scans per
//   block) to 782 blocks (~3/CU, ~2050 edges + 128-wide scans). k_colscan
//   parallelism x4 too. Aggs/gemm unchanged from R21.
// ---------------------------------------------------------------------------

typedef __attribute__((ext_vector_type(8))) short bf16x8;
typedef __attribute__((ext_vector_type(4))) float f32x4;
typedef __attribute__((ext_vector_type(2))) float f32x2;

#define CHUNKS 1024
#define BUKSZ 128

__device__ __forceinline__ unsigned short f2bf(float f) {
    unsigned u = __float_as_uint(f);
    u += 0x7FFFu + ((u >> 16) & 1u);   // round-to-nearest-even
    return (unsigned short)(u >> 16);
}
__device__ __forceinline__ unsigned packbf(float a, float b) {
    return (unsigned)f2bf(a) | ((unsigned)f2bf(b) << 16);
}
// fp8 e4m3 (OCP on gfx950) encode/decode via HW converts
__device__ __forceinline__ unsigned char f2fp8(float f) {
    return (unsigned char)(__builtin_amdgcn_cvt_pk_fp8_f32(f, f, 0u, false) & 0xFFu);
}
// accumulate 8 fp8 (one uint2) into 4 packed f32x2 accumulators
__device__ __forceinline__ void fp8add(uint2 g, f32x2* a) {
    a[0] += __builtin_amdgcn_cvt_pk_f32_fp8((int)g.x, false);
    a[1] += __builtin_amdgcn_cvt_pk_f32_fp8((int)g.x, true);
    a[2] += __builtin_amdgcn_cvt_pk_f32_fp8((int)g.y, false);
    a[3] += __builtin_amdgcn_cvt_pk_f32_fp8((int)g.y, true);
}

// ---- CSR build: bucketed counting sort (no global atomics), 128-node buckets
__global__ __launch_bounds__(256) void k_hist(const int* __restrict__ col, int E,
                                              int NBUK, int CH,
                                              int* __restrict__ hist_g) {
    __shared__ int h[1024];
    for (int i = threadIdx.x; i < NBUK; i += 256) h[i] = 0;
    __syncthreads();
    int base = blockIdx.x * CH, hi = min(base + CH, E);
    for (int e = base + (int)threadIdx.x; e < hi; e += 256)
        atomicAdd(&h[col[e] >> 7], 1);
    __syncthreads();
    for (int i = threadIdx.x; i < NBUK; i += 256)
        hist_g[blockIdx.x * NBUK + i] = h[i];
}

__global__ __launch_bounds__(256) void k_colscan(const int* __restrict__ hist_g, int NBUK,
                                                 int* __restrict__ histOff,
                                                 int* __restrict__ bucketTotal) {
    __shared__ int s[256];
    const int b = blockIdx.x, t = threadIdx.x;
    int v[4], sum = 0;
#pragma unroll
    for (int j = 0; j < 4; ++j) {
        v[j] = hist_g[(t * 4 + j) * NBUK + b];
        sum += v[j];
    }
    s[t] = sum;
    __syncthreads();
    for (int off = 1; off < 256; off <<= 1) {
        int u = (t >= off) ? s[t - off] : 0;
        __syncthreads();
        s[t] += u;
        __syncthreads();
    }
    int run = s[t] - sum;
#pragma unroll
    for (int j = 0; j < 4; ++j) {
        histOff[b * CHUNKS + t * 4 + j] = run;
        run += v[j];
    }
    if (t == 255) bucketTotal[b] = run;
}

// scan up to 1024 bucket totals (4 per thread)
__global__ __launch_bounds__(256) void k_scan_tot(const int* __restrict__ bucketTotal,
                                                  int NBUK, int E, int N,
                                                  int* __restrict__ bucketBase,
                                                  int* __restrict__ row_off) {
    __shared__ int s[256];
    const int t = threadIdx.x;
    int v[4], sum = 0;
#pragma unroll
    for (int j = 0; j < 4; ++j) {
        int idx = t * 4 + j;
        v[j] = (idx < NBUK) ? bucketTotal[idx] : 0;
        sum += v[j];
    }
    s[t] = sum;
    __syncthreads();
    for (int off = 1; off < 256; off <<= 1) {
        int u = (t >= off) ? s[t - off] : 0;
        __syncthreads();
        s[t] += u;
        __syncthreads();
    }
    int run = s[t] - sum;
#pragma unroll
    for (int j = 0; j < 4; ++j) {
        int idx = t * 4 + j;
        if (idx < NBUK) bucketBase[idx] = run;
        run += v[j];
    }
    if (t == 0) row_off[N] = E;
}

__global__ __launch_bounds__(256) void k_scatter(const int* __restrict__ row,
                                                 const int* __restrict__ col, int E,
                                                 int NBUK, int CH,
                                                 const int* __restrict__ bucketBase,
                                                 const int* __restrict__ histOff,
                                                 unsigned* __restrict__ ebuf) {
    __shared__ int cur[1024];
    for (int i = threadIdx.x; i < NBUK; i += 256)
        cur[i] = bucketBase[i] + histOff[i * CHUNKS + blockIdx.x];
    __syncthreads();
    int base = blockIdx.x * CH, hi = min(base + CH, E);
    for (int e = base + (int)threadIdx.x; e < hi; e += 256) {
        int d = col[e], src = row[e];
        int b = d >> 7;
        int pos = atomicAdd(&cur[b], 1);             // LDS atomic
        ebuf[pos] = ((unsigned)(d & (BUKSZ - 1)) << 17) | (unsigned)src;
    }
}

__global__ __launch_bounds__(512) void k_bucket(const unsigned* __restrict__ ebuf,
                                                const int* __restrict__ bucketBase,
                                                const int* __restrict__ bucketTotal,
                                                int N,
                                                int* __restrict__ row_off,
                                                float* __restrict__ dinv,
                                                int* __restrict__ csr_src) {
    __shared__ int hc[BUKSZ], of[BUKSZ];
    const int bid = blockIdx.x, t = threadIdx.x;
    const int base = bucketBase[bid];
    const int cnt  = bucketTotal[bid];
    if (t < BUKSZ) hc[t] = 0;
    __syncthreads();
    for (int i = t; i < cnt; i += 512)
        atomicAdd(&hc[ebuf[base + i] >> 17], 1);
    __syncthreads();
    int v = 0;
    if (t < BUKSZ) {
        v = hc[t];
        of[t] = v;
    }
    __syncthreads();
    for (int off = 1; off < BUKSZ; off <<= 1) {
        int u = (t >= off && t < BUKSZ) ? of[t - off] : 0;
        __syncthreads();
        if (t < BUKSZ) of[t] += u;
        __syncthreads();
    }
    if (t < BUKSZ) {
        int excl = of[t] - v;
        int node = bid * BUKSZ + t;
        if (node < N) {
            row_off[node] = base + excl;
            dinv[node] = rsqrtf((float)(v + 1));   // +1 self loop
        }
        of[t] = excl;
    }
    __syncthreads();
    for (int i = t; i < cnt; i += 512) {
        unsigned e = ebuf[base + i];
        int dl = (int)(e >> 17), src = (int)(e & 0x1FFFFu);
        int pos = atomicAdd(&of[dl], 1);       // LDS atomic
        csr_src[base + pos] = src;
    }
}

// ---- MFMA GEMM layer 1: xl = fp8((x@W1)*dinv) -----------------------------
template <int K>
__global__ __launch_bounds__(256) void k_gemm_mfma(const float* __restrict__ xf,
                                                   const float* __restrict__ W,
                                                   const float* __restrict__ dinv,
                                                   unsigned char* __restrict__ out,
                                                   int N) {
    constexpr int KS = K + 8;
    __shared__ short sX[64 * KS];
    __shared__ short sW[64 * KS];
    const int tid = threadIdx.x;
    const int wv = tid >> 6, lane = tid & 63;
    const int q = lane >> 4, m = lane & 15;
    const int nb = blockIdx.x * 64;

    for (int i = tid; i < K * 64; i += 256) {
        int k = i >> 6, c = i & 63;
        sW[c * KS + k] = (short)f2bf(W[i]);
    }
    for (int i = tid; i < 64 * (K / 8); i += 256) {
        int r = i / (K / 8), c8 = (i % (K / 8)) * 8;
        int node = nb + r;
        uint4 v = make_uint4(0u, 0u, 0u, 0u);
        if (node < N) {
            float4 lo = *(const float4*)(xf + (size_t)node * K + c8);
            float4 hi = *(const float4*)(xf + (size_t)node * K + c8 + 4);
            v.x = packbf(lo.x, lo.y);
            v.y = packbf(lo.z, lo.w);
            v.z = packbf(hi.x, hi.y);
            v.w = packbf(hi.z, hi.w);
        }
        *(uint4*)(&sX[r * KS + c8]) = v;
    }
    __syncthreads();

    f32x4 acc[4] = {};
    const short* aRow = &sX[(wv * 16 + m) * KS + q * 8];
#pragma unroll
    for (int k0 = 0; k0 < K; k0 += 32) {
        bf16x8 a = *(const bf16x8*)(aRow + k0);
#pragma unroll
        for (int ft = 0; ft < 4; ++ft) {
            bf16x8 b = *(const bf16x8*)(&sW[(ft * 16 + m) * KS + k0 + q * 8]);
            acc[ft] = __builtin_amdgcn_mfma_f32_16x16x32_bf16(a, b, acc[ft], 0, 0, 0);
        }
    }
#pragma unroll
    for (int r = 0; r < 4; ++r) {
        int node = nb + wv * 16 + q * 4 + r;
        if (node < N) {
            float di = dinv[node];
#pragma unroll
            for (int ft = 0; ft < 4; ++ft)
                out[(size_t)node * 64 + ft * 16 + m] = f2fp8(acc[ft][r] * di);
        }
    }
}

// ---- fused layer-1 agg + gemm2 (fp8 gather table, fp8 xl2 output) ---------
__global__ __launch_bounds__(256) void k_agg_g2(const unsigned char* __restrict__ xl,
                                                const int* __restrict__ row_off,
                                                const int* __restrict__ csr_src,
                                                const float* __restrict__ dinv,
                                                const float* __restrict__ bias,
                                                const float* __restrict__ W2,
                                                unsigned char* __restrict__ out, int N) {
    constexpr int KS = 72;               // 64 + 8 pad (bf16 elems)
    __shared__ short sH[4 * 16 * KS];    // per-wave 16x64 A-tiles (9KB)
    __shared__ short sW2[64 * KS];       // W2^T bf16 (9KB)
    const int tid = threadIdx.x;
    const int wv = tid >> 6, lane = tid & 63;
    const int s = lane >> 3, o = lane & 7;
    const int q = lane >> 4, m = lane & 15;

    // stage W2 transposed bf16: sW2[n*KS+k] = bf16(W2[k*64+n])
    for (int i = tid; i < 64 * 64; i += 256) {
        int k = i >> 6, n = i & 63;
        sW2[n * KS + k] = (short)f2bf(W2[i]);
    }
    // zero this wave's A-tile rows 8-15 (never written by gather phase)
    short* myH = &sH[wv * 16 * KS];
    for (int i = lane; i < 8 * KS / 4; i += 64)
        ((unsigned long long*)(myH + 8 * KS))[i] = 0ull;
    __syncthreads();                     // sW2 visible to all waves

    const int base8 = (blockIdx.x * 4 + wv) * 8;
    int node = base8 + s;
    const bool active = node < N;
    node = min(node, N - 1);
    const int beg = row_off[node];
    const int deg = row_off[node + 1] - beg;
    const int cnt = active ? deg + 1 : 0;
    int mx = cnt;
    mx = max(mx, __shfl_xor(mx, 8, 64));
    mx = max(mx, __shfl_xor(mx, 16, 64));
    mx = max(mx, __shfl_xor(mx, 32, 64));
    const char* xlb = (const char*)xl;
    const unsigned loff = (unsigned)(o << 3);          // 8B per octet
    f32x2 acc0[4] = {}, acc1[4] = {};
    int idx[4];
#pragma unroll
    for (int j = 0; j < 4; ++j) idx[j] = (j < deg) ? csr_src[beg + j] : node;
    for (int it = 0; it < mx; it += 4) {
        int c[4];
        bool v[4];
#pragma unroll
        for (int j = 0; j < 4; ++j) {
            c[j] = idx[j];
            v[j] = (it + j) < cnt;
            idx[j] = (it + 4 + j < deg) ? csr_src[beg + it + 4 + j] : node;
        }
        uint2 g0 = *(const uint2*)(xlb + (((unsigned)c[0] << 6) | loff));
        uint2 g1 = *(const uint2*)(xlb + (((unsigned)c[1] << 6) | loff));
        uint2 g2 = *(const uint2*)(xlb + (((unsigned)c[2] << 6) | loff));
        uint2 g3 = *(const uint2*)(xlb + (((unsigned)c[3] << 6) | loff));
        if (!v[0]) g0 = make_uint2(0u, 0u);
        if (!v[1]) g1 = make_uint2(0u, 0u);
        if (!v[2]) g2 = make_uint2(0u, 0u);
        if (!v[3]) g3 = make_uint2(0u, 0u);
        fp8add(g0, acc0);
        fp8add(g1, acc1);
        fp8add(g2, acc0);
        fp8add(g3, acc1);
    }
#pragma unroll
    for (int j = 0; j < 4; ++j) acc0[j] += acc1[j];
    // h1 row -> LDS A-tile (bf16), row = slot s
    {
        float di = dinv[node];
        float4 blo = *(const float4*)(bias + o * 8);
        float4 bhi = *(const float4*)(bias + o * 8 + 4);
        uint4 h;
        h.x = packbf(fmaxf(acc0[0].x * di + blo.x, 0.f), fmaxf(acc0[0].y * di + blo.y, 0.f));
        h.y = packbf(fmaxf(acc0[1].x * di + blo.z, 0.f), fmaxf(acc0[1].y * di + blo.w, 0.f));
        h.z = packbf(fmaxf(acc0[2].x * di + bhi.x, 0.f), fmaxf(acc0[2].y * di + bhi.y, 0.f));
        h.w = packbf(fmaxf(acc0[3].x * di + bhi.z, 0.f), fmaxf(acc0[3].y * di + bhi.w, 0.f));
        *(uint4*)(myH + s * KS + o * 8) = h;     // same-wave LDS, no barrier
    }
    // gemm2: 8 MFMA (4 feat-tiles x K=64)
    f32x4 accm[4] = {};
#pragma unroll
    for (int k0 = 0; k0 < 64; k0 += 32) {
        bf16x8 a = *(const bf16x8*)(myH + m * KS + q * 8 + k0);
#pragma unroll
        for (int ft = 0; ft < 4; ++ft) {
            bf16x8 b = *(const bf16x8*)(&sW2[(ft * 16 + m) * KS + k0 + q * 8]);
            accm[ft] = __builtin_amdgcn_mfma_f32_16x16x32_bf16(a, b, accm[ft], 0, 0, 0);
        }
    }
    if (q < 2) {                          // valid rows 0..7
#pragma unroll
        for (int r = 0; r < 4; ++r) {
            int node2 = base8 + q * 4 + r;
            if (node2 < N) {
                float di2 = dinv[node2];
#pragma unroll
                for (int ft = 0; ft < 4; ++ft)
                    out[(size_t)node2 * 64 + ft * 16 + m] = f2fp8(accm[ft][r] * di2);
            }
        }
    }
}

// Layer-2 agg + final FC + sigmoid (fp8 table, 4-way chains).
__global__ __launch_bounds__(256) void k_agg_fc(const unsigned char* __restrict__ xl,
                                                const int* __restrict__ row_off,
                                                const int* __restrict__ csr_src,
                                                const float* __restrict__ dinv,
                                                const float* __restrict__ bias,
                                                const float* __restrict__ Wfc,
                                                const float* __restrict__ bfc,
                                                float* __restrict__ out, int N) {
    const int wave = threadIdx.x >> 6, lane = threadIdx.x & 63;
    const int s = lane >> 3, o = lane & 7;
    int node = (blockIdx.x * 4 + wave) * 8 + s;
    const bool active = node < N;
    node = min(node, N - 1);
    const int beg = row_off[node];
    const int deg = row_off[node + 1] - beg;
    const int cnt = active ? deg + 1 : 0;
    int mx = cnt;
    mx = max(mx, __shfl_xor(mx, 8, 64));
    mx = max(mx, __shfl_xor(mx, 16, 64));
    mx = max(mx, __shfl_xor(mx, 32, 64));
    const char* xlb = (const char*)xl;
    const unsigned loff = (unsigned)(o << 3);          // 8B per octet
    f32x2 acc0[4] = {}, acc1[4] = {};
    int idx[4];
#pragma unroll
    for (int j = 0; j < 4; ++j) idx[j] = (j < deg) ? csr_src[beg + j] : node;
    for (int it = 0; it < mx; it += 4) {
        int c[4];
        bool v[4];
#pragma unroll
        for (int j = 0; j < 4; ++j) {
            c[j] = idx[j];
            v[j] = (it + j) < cnt;
            idx[j] = (it + 4 + j < deg) ? csr_src[beg + it + 4 + j] : node;
        }
        uint2 g0 = *(const uint2*)(xlb + (((unsigned)c[0] << 6) | loff));
        uint2 g1 = *(const uint2*)(xlb + (((unsigned)c[1] << 6) | loff));
        uint2 g2 = *(const uint2*)(xlb + (((unsigned)c[2] << 6) | loff));
        uint2 g3 = *(const uint2*)(xlb + (((unsigned)c[3] << 6) | loff));
        if (!v[0]) g0 = make_uint2(0u, 0u);
        if (!v[1]) g1 = make_uint2(0u, 0u);
        if (!v[2]) g2 = make_uint2(0u, 0u);
        if (!v[3]) g3 = make_uint2(0u, 0u);
        fp8add(g0, acc0);
        fp8add(g1, acc1);
        fp8add(g2, acc0);
        fp8add(g3, acc1);
    }
#pragma unroll
    for (int j = 0; j < 4; ++j) acc0[j] += acc1[j];
    const float di = dinv[node];
    float4 blo = *(const float4*)(bias + o * 8);
    float4 bhi = *(const float4*)(bias + o * 8 + 4);
    float4 wlo = *(const float4*)(Wfc + o * 8);
    float4 whi = *(const float4*)(Wfc + o * 8 + 4);
    float v = 0.f;
    v += fmaxf(acc0[0].x * di + blo.x, 0.f) * wlo.x;
    v += fmaxf(acc0[0].y * di + blo.y, 0.f) * wlo.y;
    v += fmaxf(acc0[1].x * di + blo.z, 0.f) * wlo.z;
    v += fmaxf(acc0[1].y * di + blo.w, 0.f) * wlo.w;
    v += fmaxf(acc0[2].x * di + bhi.x, 0.f) * whi.x;
    v += fmaxf(acc0[2].y * di + bhi.y, 0.f) * whi.y;
    v += fmaxf(acc0[3].x * di + bhi.z, 0.f) * whi.z;
    v += fmaxf(acc0[3].y * di + bhi.w, 0.f) * whi.w;
    v += __shfl_xor(v, 1, 64);
    v += __shfl_xor(v, 2, 64);
    v += __shfl_xor(v, 4, 64);
    if (active && o == 0) out[node] = 1.f / (1.f + expf(-(v + bfc[0])));
}

extern "C" void kernel_launch(void* const* d_in, const int* in_sizes, int n_in,
                              void* d_out, int out_size, void* d_ws, size_t ws_size,
                              hipStream_t stream) {
    const float* x   = (const float*)d_in[0];
    const int*   ei  = (const int*)d_in[1];   // [2, E]: row then col
    const float* W1  = (const float*)d_in[2];
    const float* b1  = (const float*)d_in[3];
    const float* W2  = (const float*)d_in[4];
    const float* b2  = (const float*)d_in[5];
    const float* Wfc = (const float*)d_in[6];
    const float* bfc = (const float*)d_in[7];
    float* out = (float*)d_out;

    const int H = in_sizes[3];          // 64
    const int D = in_sizes[2] / H;      // 128
    const int N = in_sizes[0] / D;      // 100000
    const int E = in_sizes[1] / 2;      // 1600000
    const int* row = ei;
    const int* col = ei + E;
    const int NBUK = (N + BUKSZ - 1) / BUKSZ;  // 782 buckets of 128 nodes
    const int CH   = (E + CHUNKS - 1) / CHUNKS;

    // Workspace carve-up (256B aligned slices)
    char* p = (char*)d_ws;
    auto carve = [&](size_t bytes) {
        char* r = p;
        p += (bytes + 255) & ~(size_t)255;
        return (void*)r;
    };
    int*            hist_g      = (int*)carve((size_t)CHUNKS * 1024 * 4);
    int*            histOff     = (int*)carve((size_t)1024 * CHUNKS * 4);
    int*            bucketTotal = (int*)carve((size_t)1024 * 4);
    int*            bucketBase  = (int*)carve((size_t)1024 * 4);
    unsigned*       ebuf        = (unsigned*)carve((size_t)E * 4);
    int*            csr_src     = (int*)carve((size_t)E * 4);
    int*            row_off     = (int*)carve((size_t)(N + 1) * 4);
    float*          dinv        = (float*)carve((size_t)N * 4);
    unsigned char*  bufXL8      = (unsigned char*)carve((size_t)N * 64);
    unsigned char*  bufXL2      = (unsigned char*)carve((size_t)N * 64);
    (void)ws_size;

    const int TB = 256;
    // 1. CSR build (bucketed counting sort; no global atomics; 128-node buckets)
    k_hist<<<CHUNKS, TB, 0, stream>>>(col, E, NBUK, CH, hist_g);
    k_colscan<<<NBUK, TB, 0, stream>>>(hist_g, NBUK, histOff, bucketTotal);
    k_scan_tot<<<1, TB, 0, stream>>>(bucketTotal, NBUK, E, N, bucketBase, row_off);
    k_scatter<<<CHUNKS, TB, 0, stream>>>(row, col, E, NBUK, CH, bucketBase, histOff, ebuf);
    k_bucket<<<NBUK, 512, 0, stream>>>(ebuf, bucketBase, bucketTotal, N,
                                       row_off, dinv, csr_src);

    int gemmGrid = (N + 63) / 64;       // 1563
    int aggGrid  = (N + 31) / 32;       // 3125 (8 nodes/wave x 4 waves)
    // 2. layer 1 GEMM: xl = fp8((x@W1)*dinv)
    k_gemm_mfma<128><<<gemmGrid, TB, 0, stream>>>(x, W1, dinv, bufXL8, N);
    // 3. fused layer-1 agg + gemm2: xl2 = fp8(dinv*(relu(dinv*Agg(xl)+b1)@W2))
    k_agg_g2<<<aggGrid, TB, 0, stream>>>(bufXL8, row_off, csr_src, dinv, b1, W2, bufXL2, N);
    // 4. layer-2 agg + FC + sigmoid
    k_agg_fc<<<aggGrid, TB, 0, stream>>>(bufXL2, row_off, csr_src, dinv, b2, Wfc, bfc, out, N);
}

// Round 11
// 202.324 us; speedup vs baseline: 1.5609x; 1.0538x over previous
//
#include <hip/hip_runtime.h>
#include <math.h>

// ---------------------------------------------------------------------------
// GCN: h1 = relu(Agg(x@W1)+b1); h2 = relu(Agg(h1@W2)+b2); out = sigmoid(h2@Wfc+bfc)
// Agg(xl)[dst] = dinv[dst] * ( sum_{src->dst} xl_s[src] + xl_s[dst] )
//   where xl_s[n] = (x@W)[n] * dinv[n]   (source-side norm folded into GEMM)
// R11-R14: node-per-slot gather aggs + fused gemm2 (215.7us).
// R15-R19: depth/shape/balance/sort/NT all NULL or regress =>
//   agg tput = per-CU inflight cap / avg latency; latency set by L2-miss frac.
// R20/R21: fp8 e4m3 gather tables both layers -> 203.9us, absmax 0.0039. BEST.
// R22: global-atomic CSR -> +112us (atomic-with-return + dependent random
//   store). Calibration: old CSR build totals only ~25us.
// R23: 128-node buckets -> +9us (4x hist/histOff traffic ate the gain). REVERT.
// R24: R21 CSR (512-node buckets) + k_scan_tot ELIMINATED: k_scatter and
//   k_bucket recompute the 196-entry bucket-base prefix locally (256-wide
//   LDS scan of bucketTotal, L2-hot). 8 launches -> 7. Remaining overhead
//   bucket is ~60us of dispatch gaps + harness fill (42us, fixed).
// ---------------------------------------------------------------------------

typedef __attribute__((ext_vector_type(8))) short bf16x8;
typedef __attribute__((ext_vector_type(4))) float f32x4;
typedef __attribute__((ext_vector_type(2))) float f32x2;

#define CHUNKS 1024

__device__ __forceinline__ unsigned short f2bf(float f) {
    unsigned u = __float_as_uint(f);
    u += 0x7FFFu + ((u >> 16) & 1u);   // round-to-nearest-even
    return (unsigned short)(u >> 16);
}
__device__ __forceinline__ unsigned packbf(float a, float b) {
    return (unsigned)f2bf(a) | ((unsigned)f2bf(b) << 16);
}
// fp8 e4m3 (OCP on gfx950) encode/decode via HW converts
__device__ __forceinline__ unsigned char f2fp8(float f) {
    return (unsigned char)(__builtin_amdgcn_cvt_pk_fp8_f32(f, f, 0u, false) & 0xFFu);
}
// accumulate 8 fp8 (one uint2) into 4 packed f32x2 accumulators
__device__ __forceinline__ void fp8add(uint2 g, f32x2* a) {
    a[0] += __builtin_amdgcn_cvt_pk_f32_fp8((int)g.x, false);
    a[1] += __builtin_amdgcn_cvt_pk_f32_fp8((int)g.x, true);
    a[2] += __builtin_amdgcn_cvt_pk_f32_fp8((int)g.y, false);
    a[3] += __builtin_amdgcn_cvt_pk_f32_fp8((int)g.y, true);
}

// ---- CSR build: bucketed counting sort (no global atomics), 512-node buckets
__global__ __launch_bounds__(256) void k_hist(const int* __restrict__ col, int E,
                                              int NBUK, int CH,
                                              int* __restrict__ hist_g) {
    __shared__ int h[256];
    for (int i = threadIdx.x; i < NBUK; i += 256) h[i] = 0;
    __syncthreads();
    int base = blockIdx.x * CH, hi = min(base + CH, E);
    for (int e = base + (int)threadIdx.x; e < hi; e += 256)
        atomicAdd(&h[col[e] >> 9], 1);
    __syncthreads();
    for (int i = threadIdx.x; i < NBUK; i += 256)
        hist_g[blockIdx.x * NBUK + i] = h[i];
}

__global__ __launch_bounds__(256) void k_colscan(const int* __restrict__ hist_g, int NBUK,
                                                 int* __restrict__ histOff,
                                                 int* __restrict__ bucketTotal) {
    __shared__ int s[256];
    const int b = blockIdx.x, t = threadIdx.x;
    int v[4], sum = 0;
#pragma unroll
    for (int j = 0; j < 4; ++j) {
        v[j] = hist_g[(t * 4 + j) * NBUK + b];
        sum += v[j];
    }
    s[t] = sum;
    __syncthreads();
    for (int off = 1; off < 256; off <<= 1) {
        int u = (t >= off) ? s[t - off] : 0;
        __syncthreads();
        s[t] += u;
        __syncthreads();
    }
    int run = s[t] - sum;
#pragma unroll
    for (int j = 0; j < 4; ++j) {
        histOff[b * CHUNKS + t * 4 + j] = run;
        run += v[j];
    }
    if (t == 255) bucketTotal[b] = run;
}

// scatter: bucketBase recomputed in-block (196-entry scan of bucketTotal)
__global__ __launch_bounds__(256) void k_scatter(const int* __restrict__ row,
                                                 const int* __restrict__ col, int E,
                                                 int NBUK, int CH,
                                                 const int* __restrict__ bucketTotal,
                                                 const int* __restrict__ histOff,
                                                 unsigned* __restrict__ ebuf) {
    __shared__ int sB[256];
    __shared__ int cur[256];
    const int t = threadIdx.x;
    int v = (t < NBUK) ? bucketTotal[t] : 0;
    sB[t] = v;
    __syncthreads();
    for (int off = 1; off < 256; off <<= 1) {
        int u = (t >= off) ? sB[t - off] : 0;
        __syncthreads();
        sB[t] += u;
        __syncthreads();
    }
    if (t < NBUK)
        cur[t] = (sB[t] - v) + histOff[t * CHUNKS + blockIdx.x];
    __syncthreads();
    int base = blockIdx.x * CH, hi = min(base + CH, E);
    for (int e = base + (int)threadIdx.x; e < hi; e += 256) {
        int d = col[e], src = row[e];
        int b = d >> 9;
        int pos = atomicAdd(&cur[b], 1);             // LDS atomic
        ebuf[pos] = ((unsigned)(d & 511) << 17) | (unsigned)src;
    }
}

// bucket: base recomputed in-block (196-entry scan); row_off[N]=E by block 0
__global__ __launch_bounds__(512) void k_bucket(const unsigned* __restrict__ ebuf,
                                                const int* __restrict__ bucketTotal,
                                                int N, int E, int NBUK,
                                                int* __restrict__ row_off,
                                                float* __restrict__ dinv,
                                                int* __restrict__ csr_src) {
    __shared__ int sB[256];
    __shared__ int hc[512], of[512];
    const int bid = blockIdx.x, t = threadIdx.x;
    if (t < 256) {
        int v = (t < NBUK) ? bucketTotal[t] : 0;
        sB[t] = v;
    }
    __syncthreads();
    for (int off = 1; off < 256; off <<= 1) {
        int u = (t >= off && t < 256) ? sB[t - off] : 0;
        __syncthreads();
        if (t < 256) sB[t] += u;
        __syncthreads();
    }
    const int cnt  = bucketTotal[bid];
    const int base = sB[bid] - cnt;          // exclusive prefix at bid
    if (bid == 0 && t == 0) row_off[N] = E;
    hc[t] = 0;
    __syncthreads();
    for (int i = t; i < cnt; i += 512)
        atomicAdd(&hc[ebuf[base + i] >> 17], 1);
    __syncthreads();
    int v = hc[t];
    of[t] = v;
    __syncthreads();
    for (int off = 1; off < 512; off <<= 1) {
        int u = (t >= off) ? of[t - off] : 0;
        __syncthreads();
        of[t] += u;
        __syncthreads();
    }
    int excl = of[t] - v;
    int node = bid * 512 + t;
    if (node < N) {
        row_off[node] = base + excl;
        dinv[node] = rsqrtf((float)(v + 1));   // +1 self loop
    }
    of[t] = excl;
    __syncthreads();
    for (int i = t; i < cnt; i += 512) {
        unsigned e = ebuf[base + i];
        int dl = (int)(e >> 17), src = (int)(e & 0x1FFFFu);
        int pos = atomicAdd(&of[dl], 1);       // LDS atomic
        csr_src[base + pos] = src;
    }
}

// ---- MFMA GEMM layer 1: xl = fp8((x@W1)*dinv) -----------------------------
template <int K>
__global__ __launch_bounds__(256) void k_gemm_mfma(const float* __restrict__ xf,
                                                   const float* __restrict__ W,
                                                   const float* __restrict__ dinv,
                                                   unsigned char* __restrict__ out,
                                                   int N) {
    constexpr int KS = K + 8;
    __shared__ short sX[64 * KS];
    __shared__ short sW[64 * KS];
    const int tid = threadIdx.x;
    const int wv = tid >> 6, lane = tid & 63;
    const int q = lane >> 4, m = lane & 15;
    const int nb = blockIdx.x * 64;

    for (int i = tid; i < K * 64; i += 256) {
        int k = i >> 6, c = i & 63;
        sW[c * KS + k] = (short)f2bf(W[i]);
    }
    for (int i = tid; i < 64 * (K / 8); i += 256) {
        int r = i / (K / 8), c8 = (i % (K / 8)) * 8;
        int node = nb + r;
        uint4 v = make_uint4(0u, 0u, 0u, 0u);
        if (node < N) {
            float4 lo = *(const float4*)(xf + (size_t)node * K + c8);
            float4 hi = *(const float4*)(xf + (size_t)node * K + c8 + 4);
            v.x = packbf(lo.x, lo.y);
            v.y = packbf(lo.z, lo.w);
            v.z = packbf(hi.x, hi.y);
            v.w = packbf(hi.z, hi.w);
        }
        *(uint4*)(&sX[r * KS + c8]) = v;
    }
    __syncthreads();

    f32x4 acc[4] = {};
    const short* aRow = &sX[(wv * 16 + m) * KS + q * 8];
#pragma unroll
    for (int k0 = 0; k0 < K; k0 += 32) {
        bf16x8 a = *(const bf16x8*)(aRow + k0);
#pragma unroll
        for (int ft = 0; ft < 4; ++ft) {
            bf16x8 b = *(const bf16x8*)(&sW[(ft * 16 + m) * KS + k0 + q * 8]);
            acc[ft] = __builtin_amdgcn_mfma_f32_16x16x32_bf16(a, b, acc[ft], 0, 0, 0);
        }
    }
#pragma unroll
    for (int r = 0; r < 4; ++r) {
        int node = nb + wv * 16 + q * 4 + r;
        if (node < N) {
            float di = dinv[node];
#pragma unroll
            for (int ft = 0; ft < 4; ++ft)
                out[(size_t)node * 64 + ft * 16 + m] = f2fp8(acc[ft][r] * di);
        }
    }
}

// ---- fused layer-1 agg + gemm2 (fp8 gather table, fp8 xl2 output) ---------
__global__ __launch_bounds__(256) void k_agg_g2(const unsigned char* __restrict__ xl,
                                                const int* __restrict__ row_off,
                                                const int* __restrict__ csr_src,
                                                const float* __restrict__ dinv,
                                                const float* __restrict__ bias,
                                                const float* __restrict__ W2,
                                                unsigned char* __restrict__ out, int N) {
    constexpr int KS = 72;               // 64 + 8 pad (bf16 elems)
    __shared__ short sH[4 * 16 * KS];    // per-wave 16x64 A-tiles (9KB)
    __shared__ short sW2[64 * KS];       // W2^T bf16 (9KB)
    const int tid = threadIdx.x;
    const int wv = tid >> 6, lane = tid & 63;
    const int s = lane >> 3, o = lane & 7;
    const int q = lane >> 4, m = lane & 15;

    // stage W2 transposed bf16: sW2[n*KS+k] = bf16(W2[k*64+n])
    for (int i = tid; i < 64 * 64; i += 256) {
        int k = i >> 6, n = i & 63;
        sW2[n * KS + k] = (short)f2bf(W2[i]);
    }
    // zero this wave's A-tile rows 8-15 (never written by gather phase)
    short* myH = &sH[wv * 16 * KS];
    for (int i = lane; i < 8 * KS / 4; i += 64)
        ((unsigned long long*)(myH + 8 * KS))[i] = 0ull;
    __syncthreads();                     // sW2 visible to all waves

    const int base8 = (blockIdx.x * 4 + wv) * 8;
    int node = base8 + s;
    const bool active = node < N;
    node = min(node, N - 1);
    const int beg = row_off[node];
    const int deg = row_off[node + 1] - beg;
    const int cnt = active ? deg + 1 : 0;
    int mx = cnt;
    mx = max(mx, __shfl_xor(mx, 8, 64));
    mx = max(mx, __shfl_xor(mx, 16, 64));
    mx = max(mx, __shfl_xor(mx, 32, 64));
    const char* xlb = (const char*)xl;
    const unsigned loff = (unsigned)(o << 3);          // 8B per octet
    f32x2 acc0[4] = {}, acc1[4] = {};
    int idx[4];
#pragma unroll
    for (int j = 0; j < 4; ++j) idx[j] = (j < deg) ? csr_src[beg + j] : node;
    for (int it = 0; it < mx; it += 4) {
        int c[4];
        bool v[4];
#pragma unroll
        for (int j = 0; j < 4; ++j) {
            c[j] = idx[j];
            v[j] = (it + j) < cnt;
            idx[j] = (it + 4 + j < deg) ? csr_src[beg + it + 4 + j] : node;
        }
        uint2 g0 = *(const uint2*)(xlb + (((unsigned)c[0] << 6) | loff));
        uint2 g1 = *(const uint2*)(xlb + (((unsigned)c[1] << 6) | loff));
        uint2 g2 = *(const uint2*)(xlb + (((unsigned)c[2] << 6) | loff));
        uint2 g3 = *(const uint2*)(xlb + (((unsigned)c[3] << 6) | loff));
        if (!v[0]) g0 = make_uint2(0u, 0u);
        if (!v[1]) g1 = make_uint2(0u, 0u);
        if (!v[2]) g2 = make_uint2(0u, 0u);
        if (!v[3]) g3 = make_uint2(0u, 0u);
        fp8add(g0, acc0);
        fp8add(g1, acc1);
        fp8add(g2, acc0);
        fp8add(g3, acc1);
    }
#pragma unroll
    for (int j = 0; j < 4; ++j) acc0[j] += acc1[j];
    // h1 row -> LDS A-tile (bf16), row = slot s
    {
        float di = dinv[node];
        float4 blo = *(const float4*)(bias + o * 8);
        float4 bhi = *(const float4*)(bias + o * 8 + 4);
        uint4 h;
        h.x = packbf(fmaxf(acc0[0].x * di + blo.x, 0.f), fmaxf(acc0[0].y * di + blo.y, 0.f));
        h.y = packbf(fmaxf(acc0[1].x * di + blo.z, 0.f), fmaxf(acc0[1].y * di + blo.w, 0.f));
        h.z = packbf(fmaxf(acc0[2].x * di + bhi.x, 0.f), fmaxf(acc0[2].y * di + bhi.y, 0.f));
        h.w = packbf(fmaxf(acc0[3].x * di + bhi.z, 0.f), fmaxf(acc0[3].y * di + bhi.w, 0.f));
        *(uint4*)(myH + s * KS + o * 8) = h;     // same-wave LDS, no barrier
    }
    // gemm2: 8 MFMA (4 feat-tiles x K=64)
    f32x4 accm[4] = {};
#pragma unroll
    for (int k0 = 0; k0 < 64; k0 += 32) {
        bf16x8 a = *(const bf16x8*)(myH + m * KS + q * 8 + k0);
#pragma unroll
        for (int ft = 0; ft < 4; ++ft) {
            bf16x8 b = *(const bf16x8*)(&sW2[(ft * 16 + m) * KS + k0 + q * 8]);
            accm[ft] = __builtin_amdgcn_mfma_f32_16x16x32_bf16(a, b, accm[ft], 0, 0, 0);
        }
    }
    if (q < 2) {                          // valid rows 0..7
#pragma unroll
        for (int r = 0; r < 4; ++r) {
            int node2 = base8 + q * 4 + r;
            if (node2 < N) {
                float di2 = dinv[node2];
#pragma unroll
                for (int ft = 0; ft < 4; ++ft)
                    out[(size_t)node2 * 64 + ft * 16 + m] = f2fp8(accm[ft][r] * di2);
            }
        }
    }
}

// Layer-2 agg + final FC + sigmoid (fp8 table, 4-way chains).
__global__ __launch_bounds__(256) void k_agg_fc(const unsigned char* __restrict__ xl,
                                                const int* __restrict__ row_off,
                                                const int* __restrict__ csr_src,
                                                const float* __restrict__ dinv,
                                                const float* __restrict__ bias,
                                                const float* __restrict__ Wfc,
                                                const float* __restrict__ bfc,
                                                float* __restrict__ out, int N) {
    const int wave = threadIdx.x >> 6, lane = threadIdx.x & 63;
    const int s = lane >> 3, o = lane & 7;
    int node = (blockIdx.x * 4 + wave) * 8 + s;
    const bool active = node < N;
    node = min(node, N - 1);
    const int beg = row_off[node];
    const int deg = row_off[node + 1] - beg;
    const int cnt = active ? deg + 1 : 0;
    int mx = cnt;
    mx = max(mx, __shfl_xor(mx, 8, 64));
    mx = max(mx, __shfl_xor(mx, 16, 64));
    mx = max(mx, __shfl_xor(mx, 32, 64));
    const char* xlb = (const char*)xl;
    const unsigned loff = (unsigned)(o << 3);          // 8B per octet
    f32x2 acc0[4] = {}, acc1[4] = {};
    int idx[4];
#pragma unroll
    for (int j = 0; j < 4; ++j) idx[j] = (j < deg) ? csr_src[beg + j] : node;
    for (int it = 0; it < mx; it += 4) {
        int c[4];
        bool v[4];
#pragma unroll
        for (int j = 0; j < 4; ++j) {
            c[j] = idx[j];
            v[j] = (it + j) < cnt;
            idx[j] = (it + 4 + j < deg) ? csr_src[beg + it + 4 + j] : node;
        }
        uint2 g0 = *(const uint2*)(xlb + (((unsigned)c[0] << 6) | loff));
        uint2 g1 = *(const uint2*)(xlb + (((unsigned)c[1] << 6) | loff));
        uint2 g2 = *(const uint2*)(xlb + (((unsigned)c[2] << 6) | loff));
        uint2 g3 = *(const uint2*)(xlb + (((unsigned)c[3] << 6) | loff));
        if (!v[0]) g0 = make_uint2(0u, 0u);
        if (!v[1]) g1 = make_uint2(0u, 0u);
        if (!v[2]) g2 = make_uint2(0u, 0u);
        if (!v[3]) g3 = make_uint2(0u, 0u);
        fp8add(g0, acc0);
        fp8add(g1, acc1);
        fp8add(g2, acc0);
        fp8add(g3, acc1);
    }
#pragma unroll
    for (int j = 0; j < 4; ++j) acc0[j] += acc1[j];
    const float di = dinv[node];
    float4 blo = *(const float4*)(bias + o * 8);
    float4 bhi = *(const float4*)(bias + o * 8 + 4);
    float4 wlo = *(const float4*)(Wfc + o * 8);
    float4 whi = *(const float4*)(Wfc + o * 8 + 4);
    float v = 0.f;
    v += fmaxf(acc0[0].x * di + blo.x, 0.f) * wlo.x;
    v += fmaxf(acc0[0].y * di + blo.y, 0.f) * wlo.y;
    v += fmaxf(acc0[1].x * di + blo.z, 0.f) * wlo.z;
    v += fmaxf(acc0[1].y * di + blo.w, 0.f) * wlo.w;
    v += fmaxf(acc0[2].x * di + bhi.x, 0.f) * whi.x;
    v += fmaxf(acc0[2].y * di + bhi.y, 0.f) * whi.y;
    v += fmaxf(acc0[3].x * di + bhi.z, 0.f) * whi.z;
    v += fmaxf(acc0[3].y * di + bhi.w, 0.f) * whi.w;
    v += __shfl_xor(v, 1, 64);
    v += __shfl_xor(v, 2, 64);
    v += __shfl_xor(v, 4, 64);
    if (active && o == 0) out[node] = 1.f / (1.f + expf(-(v + bfc[0])));
}

extern "C" void kernel_launch(void* const* d_in, const int* in_sizes, int n_in,
                              void* d_out, int out_size, void* d_ws, size_t ws_size,
                              hipStream_t stream) {
    const float* x   = (const float*)d_in[0];
    const int*   ei  = (const int*)d_in[1];   // [2, E]: row then col
    const float* W1  = (const float*)d_in[2];
    const float* b1  = (const float*)d_in[3];
    const float* W2  = (const float*)d_in[4];
    const float* b2  = (const float*)d_in[5];
    const float* Wfc = (const float*)d_in[6];
    const float* bfc = (const float*)d_in[7];
    float* out = (float*)d_out;

    const int H = in_sizes[3];          // 64
    const int D = in_sizes[2] / H;      // 128
    const int N = in_sizes[0] / D;      // 100000
    const int E = in_sizes[1] / 2;      // 1600000
    const int* row = ei;
    const int* col = ei + E;
    const int NBUK = (N + 511) >> 9;    // 196 buckets of 512 nodes
    const int CH   = (E + CHUNKS - 1) / CHUNKS;

    // Workspace carve-up (256B aligned slices)
    char* p = (char*)d_ws;
    auto carve = [&](size_t bytes) {
        char* r = p;
        p += (bytes + 255) & ~(size_t)255;
        return (void*)r;
    };
    int*            hist_g      = (int*)carve((size_t)CHUNKS * 256 * 4);
    int*            histOff     = (int*)carve((size_t)256 * CHUNKS * 4);
    int*            bucketTotal = (int*)carve((size_t)256 * 4);
    unsigned*       ebuf        = (unsigned*)carve((size_t)E * 4);
    int*            csr_src     = (int*)carve((size_t)E * 4);
    int*            row_off     = (int*)carve((size_t)(N + 1) * 4);
    float*          dinv        = (float*)carve((size_t)N * 4);
    unsigned char*  bufXL8      = (unsigned char*)carve((size_t)N * 64);
    unsigned char*  bufXL2      = (unsigned char*)carve((size_t)N * 64);
    (void)ws_size;

    const int TB = 256;
    // 1. CSR build (bucketed counting sort; no global atomics; 512-node buckets)
    k_hist<<<CHUNKS, TB, 0, stream>>>(col, E, NBUK, CH, hist_g);
    k_colscan<<<NBUK, TB, 0, stream>>>(hist_g, NBUK, histOff, bucketTotal);
    k_scatter<<<CHUNKS, TB, 0, stream>>>(row, col, E, NBUK, CH, bucketTotal, histOff, ebuf);
    k_bucket<<<NBUK, 512, 0, stream>>>(ebuf, bucketTotal, N, E, NBUK,
                                       row_off, dinv, csr_src);

    int gemmGrid = (N + 63) / 64;       // 1563
    int aggGrid  = (N + 31) / 32;       // 3125 (8 nodes/wave x 4 waves)
    // 2. layer 1 GEMM: xl = fp8((x@W1)*dinv)
    k_gemm_mfma<128><<<gemmGrid, TB, 0, stream>>>(x, W1, dinv, bufXL8, N);
    // 3. fused layer-1 agg + gemm2: xl2 = fp8(dinv*(relu(dinv*Agg(xl)+b1)@W2))
    k_agg_g2<<<aggGrid, TB, 0, stream>>>(bufXL8, row_off, csr_src, dinv, b1, W2, bufXL2, N);
    // 4. layer-2 agg + FC + sigmoid
    k_agg_fc<<<aggGrid, TB, 0, stream>>>(bufXL2, row_off, csr_src, dinv, b2, Wfc, bfc, out, N);
}